// Round 2
// baseline (314.215 us; speedup 1.0000x reference)
//
#include <hip/hip_runtime.h>
#include <math.h>

// AFM forward: B=4096, F=39, V=100000, E=16, A=16, P=741
// out[b] = bias + sum_f emb1[f,idx]*xv + softmax-weighted sum over pairs of (wij . Pv)
// softmax scores: wij . (W1 @ H)  (b1.H is constant over pairs -> cancels in softmax)

#define BB 4096
#define FF 39
#define VV 100000
#define EE 16
#define AA 16
#define PP (FF * (FF - 1) / 2) /* 741 */
#define SSTRIDE 20             /* padded floats per field row in LDS (16B aligned, not pow2) */

__global__ __launch_bounds__(256) void afm_kernel(
    const int* __restrict__ Xi, const float* __restrict__ Xv,
    const float* __restrict__ emb1, const float* __restrict__ emb2,
    const float* __restrict__ W1, const float* __restrict__ b1,
    const float* __restrict__ H, const float* __restrict__ Pv,
    const float* __restrict__ bias, float* __restrict__ out)
{
    __shared__ float sec[FF * SSTRIDE];   // second-order rows, scaled by Xv
    __shared__ float firstv[64];          // first-order contributions (padded to a wave)
    __shared__ float WHs[EE];             // W1 @ H
    __shared__ float PvS[EE];
    __shared__ short pairtab[PP];         // (i<<8)|j per pair
    __shared__ float red[12];             // cross-wave reduce scratch
    __shared__ float m_s;

    const int b = blockIdx.x;
    const int t = threadIdx.x;

    // ---- fold W1 @ H (16 dots of length 16), copy Pv to LDS ----
    if (t < EE) {
        float s = 0.f;
#pragma unroll
        for (int a = 0; a < AA; ++a) s += W1[t * AA + a] * H[a];
        WHs[t] = s;
        PvS[t] = Pv[t];
    }
    if (t >= 64 && t < 128) firstv[t - 64] = 0.f;  // pad lanes 39..63

    // ---- build pair table: row i starts at i*(2F-1-i)/2 ----
    if (t < FF) {
        int base = t * (2 * FF - 1 - t) / 2;
        for (int j = t + 1; j < FF; ++j)
            pairtab[base + (j - t - 1)] = (short)((t << 8) | j);
    }

    // ---- gather second-order rows: thread (f,e4) loads one float4 ----
    if (t < FF * 4) {
        const int f = t >> 2, e4 = t & 3;
        const int idx = Xi[b * FF + f];
        const float xv = Xv[b * FF + f];
        const float4 v = *reinterpret_cast<const float4*>(
            emb2 + ((long)f * VV + idx) * EE + e4 * 4);
        float4 r;
        r.x = v.x * xv; r.y = v.y * xv; r.z = v.z * xv; r.w = v.w * xv;
        *reinterpret_cast<float4*>(&sec[f * SSTRIDE + e4 * 4]) = r;
    }

    // ---- first-order gathers on a disjoint thread range ----
    if (t >= 192 && t < 192 + FF) {
        const int f = t - 192;
        const int idx = Xi[b * FF + f];
        firstv[f] = emb1[(long)f * VV + idx] * Xv[b * FF + f];
    }

    __syncthreads();

    // ---- per-thread registers for the two dot vectors ----
    float wh[EE], pv[EE];
#pragma unroll
    for (int e = 0; e < EE; ++e) { wh[e] = WHs[e]; pv[e] = PvS[e]; }

    // ---- pair phase: <=3 pairs per thread, statically unrolled ----
    float sv[3], qv[3];
    float local_max = -INFINITY;
#pragma unroll
    for (int k = 0; k < 3; ++k) {
        const int p = t + k * 256;
        float s = -INFINITY, q = 0.f;
        if (p < PP) {
            const int ij = pairtab[p];
            const int i = ij >> 8, j = ij & 255;
            const float4* __restrict__ si = reinterpret_cast<const float4*>(&sec[i * SSTRIDE]);
            const float4* __restrict__ sj = reinterpret_cast<const float4*>(&sec[j * SSTRIDE]);
            s = 0.f;
#pragma unroll
            for (int e4 = 0; e4 < 4; ++e4) {
                const float4 a = si[e4];
                const float4 c = sj[e4];
                const float w0 = a.x * c.x, w1 = a.y * c.y, w2 = a.z * c.z, w3 = a.w * c.w;
                s += w0 * wh[e4 * 4 + 0] + w1 * wh[e4 * 4 + 1]
                   + w2 * wh[e4 * 4 + 2] + w3 * wh[e4 * 4 + 3];
                q += w0 * pv[e4 * 4 + 0] + w1 * pv[e4 * 4 + 1]
                   + w2 * pv[e4 * 4 + 2] + w3 * pv[e4 * 4 + 3];
            }
            local_max = fmaxf(local_max, s);
        }
        sv[k] = s; qv[k] = q;
    }

    // ---- block max reduce (wave64 shfl + LDS combine) ----
    float m = local_max;
#pragma unroll
    for (int o = 32; o > 0; o >>= 1) m = fmaxf(m, __shfl_xor(m, o, 64));
    const int wid = t >> 6;
    if ((t & 63) == 0) red[wid] = m;
    __syncthreads();
    if (t == 0) m_s = fmaxf(fmaxf(red[0], red[1]), fmaxf(red[2], red[3]));
    __syncthreads();
    m = m_s;

    // ---- fused softmax numerator/denominator; wave 0 also reduces first-order ----
    float den = 0.f, num = 0.f;
#pragma unroll
    for (int k = 0; k < 3; ++k) {
        const float e = __expf(sv[k] - m);   // exp(-inf)=0 for inactive slots
        den += e;
        num += e * qv[k];
    }
    float fs = (t < 64) ? firstv[t] : 0.f;   // lanes 39..63 padded to 0
#pragma unroll
    for (int o = 32; o > 0; o >>= 1) {
        den += __shfl_xor(den, o, 64);
        num += __shfl_xor(num, o, 64);
        fs  += __shfl_xor(fs, o, 64);
    }
    if ((t & 63) == 0) { red[wid] = den; red[4 + wid] = num; red[8 + wid] = fs; }
    __syncthreads();
    if (t == 0) {
        const float D = red[0] + red[1] + red[2] + red[3];
        const float N = red[4] + red[5] + red[6] + red[7];
        out[b] = bias[0] + red[8] + N / D;
    }
}

extern "C" void kernel_launch(void* const* d_in, const int* in_sizes, int n_in,
                              void* d_out, int out_size, void* d_ws, size_t ws_size,
                              hipStream_t stream)
{
    const int*   Xi   = (const int*)d_in[0];
    const float* Xv   = (const float*)d_in[1];
    const float* emb1 = (const float*)d_in[2];
    const float* emb2 = (const float*)d_in[3];
    const float* W1   = (const float*)d_in[4];
    const float* b1   = (const float*)d_in[5];
    const float* H    = (const float*)d_in[6];
    const float* Pv   = (const float*)d_in[7];
    const float* bias = (const float*)d_in[8];
    (void)b1; (void)in_sizes; (void)n_in; (void)out_size; (void)d_ws; (void)ws_size;

    afm_kernel<<<BB, 256, 0, stream>>>(Xi, Xv, emb1, emb2, W1, b1, H, Pv, bias,
                                       (float*)d_out);
}